// Round 10
// baseline (543.416 us; speedup 1.0000x reference)
//
#include <hip/hip_runtime.h>

#define N_NODES 65536
#define G_GRID  32768
#define E_EDGES 600000
#define HD      128

typedef __attribute__((ext_vector_type(8))) short bf8;
typedef __attribute__((ext_vector_type(4))) float f32x4;

__device__ __forceinline__ short f2bf(float f){
  union { float f; unsigned u; } v; v.f = f;
  unsigned r = v.u + 0x7FFFu + ((v.u >> 16) & 1u);
  return (short)(r >> 16);
}
__device__ __forceinline__ float bf2f(short s){
  union { unsigned u; float f; } v; v.u = ((unsigned)(unsigned short)s) << 16; return v.f;
}

__device__ __forceinline__ bf8 load_pack8(const float* p, float scale){
  float4 u0 = *(const float4*)p;
  float4 u1 = *(const float4*)(p + 4);
  bf8 r;
  r[0]=f2bf(u0.x*scale); r[1]=f2bf(u0.y*scale); r[2]=f2bf(u0.z*scale); r[3]=f2bf(u0.w*scale);
  r[4]=f2bf(u1.x*scale); r[5]=f2bf(u1.y*scale); r[6]=f2bf(u1.z*scale); r[7]=f2bf(u1.w*scale);
  return r;
}

// ---------- weight prep: transpose + bf16 ----------
__global__ void prep_w_k(const float* __restrict__ nmw1, const float* __restrict__ nmw2,
                         const float* __restrict__ emw2, const float* __restrict__ mmw1,
                         const float* __restrict__ mmw2, const float* __restrict__ umw1,
                         const float* __restrict__ umw2, short* __restrict__ dst)
{
  int i = blockIdx.x*256 + threadIdx.x;  // < 131072
  const float* src; int local; bool k256 = false;
  if      (i < 16384){ src = nmw1; local = i; }
  else if (i < 32768){ src = nmw2; local = i - 16384; }
  else if (i < 49152){ src = emw2; local = i - 32768; }
  else if (i < 81920){ src = mmw1; local = i - 49152; k256 = true; }
  else if (i < 98304){ src = mmw2; local = i - 81920; }
  else if (i < 114688){ src = umw1; local = i - 98304; }
  else               { src = umw2; local = i - 114688; }
  int n, k;
  if (k256){ n = local >> 8; k = local & 255; }
  else     { n = local >> 7; k = local & 127; }
  dst[i] = f2bf(src[k*HD + n]);
}

// ---------- fold prep: W_combo (k-split across 128 blocks), bcombo, ew1x double-bf16 ----------
// ew1x[n][32]: [wh0..5 | wh0..5 | wl0..5 | bh, bl | 0..]; pairs with A=[ph|pl|ph|1,1|0..]
__global__ void prep_combo2_k(const float* __restrict__ emw1, const float* __restrict__ eb1,
                              const float* __restrict__ emw2, const float* __restrict__ eb2,
                              const float* __restrict__ mmw1, const float* __restrict__ mb1,
                              short* __restrict__ wcombot, float* __restrict__ bcombo,
                              short* __restrict__ ew1x)
{
  if (blockIdx.x < 128){
    __shared__ float part[2][128];
    int k = blockIdx.x;
    int t = threadIdx.x, n = t & 127, half = t >> 7;
    float acc = 0.f;
    const float* er = emw2 + k*HD + half*64;
    #pragma unroll 8
    for (int j=0;j<64;j++) acc += er[j] * mmw1[(HD + half*64 + j)*HD + n];
    part[half][n] = acc;
    __syncthreads();
    if (half == 0) wcombot[n*HD + k] = f2bf(part[0][n] + part[1][n]);
  } else {
    int t = threadIdx.x;
    if (t < 128){
      int n = t;
      float acc = mb1[n];
      for (int j=0;j<HD;j++) acc += eb2[j] * mmw1[(HD + j)*HD + n];
      bcombo[n] = acc;
      short v[32];
      #pragma unroll
      for (int i=0;i<32;i++) v[i] = 0;
      #pragma unroll
      for (int i=0;i<6;i++){
        float wv = emw1[i*HD + n];
        short wh = f2bf(wv);
        short wl = f2bf(wv - bf2f(wh));
        v[i] = wh; v[6+i] = wh; v[12+i] = wl;
      }
      float bv = eb1[n];
      short bh = f2bf(bv);
      v[18] = bh; v[19] = f2bf(bv - bf2f(bh));
      #pragma unroll
      for (int i=0;i<32;i++) ew1x[n*32 + i] = v[i];
    }
  }
}

// ---------- node MLP (MFMA, wave-local hid slab -> no barrier) ----------
__global__ void node_mlp_k(const float* __restrict__ X,
                           const short* __restrict__ w1t, const float* __restrict__ b1,
                           const short* __restrict__ w2t, const float* __restrict__ b2,
                           short* __restrict__ nf)
{
  __shared__ short hid[64][136];
  const int t = threadIdx.x;
  const int wave = t >> 6, lane = t & 63, l15 = lane & 15, q = lane >> 4;
  const int rw = blockIdx.x*64 + wave*16;

  bf8 a[4];
  const float* xr = X + (size_t)(rw + l15)*HD;
  #pragma unroll
  for (int kt=0; kt<4; kt++) a[kt] = load_pack8(xr + kt*32 + q*8, 1.0f);

  #pragma unroll
  for (int ct=0; ct<8; ct++){
    f32x4 acc = {0.f,0.f,0.f,0.f};
    #pragma unroll
    for (int kt=0; kt<4; kt++){
      bf8 b = *(const bf8*)(w1t + (ct*16 + l15)*HD + kt*32 + q*8);
      acc = __builtin_amdgcn_mfma_f32_16x16x32_bf16(a[kt], b, acc, 0, 0, 0);
    }
    float bias = b1[ct*16 + l15];
    #pragma unroll
    for (int r=0;r<4;r++){
      float v = acc[r] + bias;
      v = v / (1.f + __expf(-v));
      hid[wave*16 + q*4 + r][ct*16 + l15] = f2bf(v);
    }
  }
  bf8 a2[4];
  #pragma unroll
  for (int kt=0;kt<4;kt++) a2[kt] = *(const bf8*)&hid[wave*16 + l15][kt*32 + q*8];
  #pragma unroll
  for (int ct=0; ct<8; ct++){
    f32x4 acc = {0.f,0.f,0.f,0.f};
    #pragma unroll
    for (int kt=0;kt<4;kt++){
      bf8 b = *(const bf8*)(w2t + (ct*16 + l15)*HD + kt*32 + q*8);
      acc = __builtin_amdgcn_mfma_f32_16x16x32_bf16(a2[kt], b, acc, 0, 0, 0);
    }
    float bias = b2[ct*16 + l15];
    #pragma unroll
    for (int r=0;r<4;r++)
      nf[(size_t)(rw + q*4 + r)*HD + ct*16 + l15] = f2bf(acc[r] + bias);
  }
}

// ---------- CSR build ----------
__global__ void count_k(const int* __restrict__ eidx, int* __restrict__ counts){
  int e = blockIdx.x*256 + threadIdx.x;
  if (e < E_EDGES) atomicAdd(&counts[eidx[E_EDGES + e]], 1);
}

__global__ void scan_k(const int* __restrict__ counts, int* __restrict__ offs){
  __shared__ int part[1024];
  const int t = threadIdx.x;
  const int base = t*32;
  int loc[32];
  int s = 0;
  #pragma unroll
  for (int i=0;i<32;i++){ loc[i] = s; s += counts[base+i]; }
  part[t] = s;
  __syncthreads();
  for (int off=1; off<1024; off<<=1){
    int v = (t>=off) ? part[t-off] : 0;
    __syncthreads();
    part[t] += v;
    __syncthreads();
  }
  int pre = (t==0) ? 0 : part[t-1];
  #pragma unroll
  for (int i=0;i<32;i++) offs[base+i] = pre + loc[i];
  if (t==1023) offs[G_GRID] = pre + s;
}

__global__ void scatter_k(const int* __restrict__ eidx, const int* __restrict__ offs,
                          int* __restrict__ counts,
                          int* __restrict__ srcs_s, int* __restrict__ tgts_s){
  int e = blockIdx.x*256 + threadIdx.x;
  if (e < E_EDGES){
    int g = eidx[E_EDGES + e];
    int slot = offs[g] + atomicSub(&counts[g], 1) - 1;
    srcs_s[slot] = eidx[e];
    tgts_s[slot] = g;
  }
}

// A-frag builder for double-bf16 stage1: A=[ph0..5|pl0..5 slices per quad|1,1 pad]
__device__ __forceinline__ bf8 build_af(const float p[6], int q){
  short ph[6], pl[6];
  #pragma unroll
  for (int i=0;i<6;i++){
    ph[i] = f2bf(p[i]);
    pl[i] = f2bf(p[i] - bf2f(ph[i]));
  }
  bf8 af = {0,0,0,0,0,0,0,0};
  if (q == 0){
    af[0]=ph[0]; af[1]=ph[1]; af[2]=ph[2]; af[3]=ph[3];
    af[4]=ph[4]; af[5]=ph[5]; af[6]=pl[0]; af[7]=pl[1];
  } else if (q == 1){
    af[0]=pl[2]; af[1]=pl[3]; af[2]=pl[4]; af[3]=pl[5];
    af[4]=ph[0]; af[5]=ph[1]; af[6]=ph[2]; af[7]=ph[3];
  } else if (q == 2){
    af[0]=ph[4]; af[1]=ph[5]; af[2]=(short)0x3F80; af[3]=(short)0x3F80;
  }
  return af;
}

// ---------- fused edge+message: ZERO barriers, stage1 via MFMA, LDS 35.3 KB ----------
__global__ void __launch_bounds__(256, 3)
edge_msg6_k(const int* __restrict__ srcs_s, const int* __restrict__ tgts_s,
            const float* __restrict__ npos, const float* __restrict__ gpos,
            const short* __restrict__ ew1x, const float* __restrict__ bcombo,
            const short* __restrict__ mw1t, const short* __restrict__ wcombot,
            const short* __restrict__ mw2t, const float* __restrict__ mb2,
            const short* __restrict__ nf, float* __restrict__ agg)
{
  __shared__ int tgtl[128];         // per-wave staged (lanes<32), no barrier
  __shared__ short hm[128][136];    // 34816 B -> total 35328 B

  const int t = threadIdx.x;
  const int e0 = blockIdx.x*128;
  const int w = t >> 6, lane = t & 63, l15 = lane & 15, q = lane >> 4;
  const int base = e0 + w*32;

  // ---- early gathers ----
  int i0 = base + l15;      if (i0 >= E_EDGES) i0 = E_EDGES - 1;
  int i1 = base + 16 + l15; if (i1 >= E_EDGES) i1 = E_EDGES - 1;
  int s0 = srcs_s[i0], s1 = srcs_s[i1];
  int g0 = tgts_s[i0], g1 = tgts_s[i1];

  bf8 an0[4], an1[4];
  {
    const short* n0p = nf + (size_t)s0*HD + q*8;
    const short* n1p = nf + (size_t)s1*HD + q*8;
    #pragma unroll
    for (int kt=0;kt<4;kt++){ an0[kt] = *(const bf8*)(n0p + kt*32); an1[kt] = *(const bf8*)(n1p + kt*32); }
  }
  float pA[6], pB[6];
  pA[0]=npos[s0*3+0]; pA[1]=npos[s0*3+1]; pA[2]=npos[s0*3+2];
  pA[3]=gpos[g0*3+0]; pA[4]=gpos[g0*3+1]; pA[5]=gpos[g0*3+2];
  pB[0]=npos[s1*3+0]; pB[1]=npos[s1*3+1]; pB[2]=npos[s1*3+2];
  pB[3]=gpos[g1*3+0]; pB[4]=gpos[g1*3+1]; pB[5]=gpos[g1*3+2];

  // per-wave tgt staging (wave-local write+read -> no __syncthreads)
  if (lane < 32){
    int idx = base + lane; if (idx >= E_EDGES) idx = E_EDGES - 1;
    tgtl[w*32 + lane] = tgts_s[idx];
  }

  // ---- stage 1: h = silu(pos6@ew1+eb1) via ONE MFMA per ct per tile (double-bf16, exact) ----
  bf8 af0 = build_af(pA, q);
  bf8 af1 = build_af(pB, q);
  #pragma unroll
  for (int ct=0; ct<8; ct++){
    bf8 bw = *(const bf8*)(ew1x + (ct*16 + l15)*32 + q*8);
    f32x4 h0 = {0.f,0.f,0.f,0.f}, h1 = {0.f,0.f,0.f,0.f};
    h0 = __builtin_amdgcn_mfma_f32_16x16x32_bf16(af0, bw, h0, 0,0,0);
    h1 = __builtin_amdgcn_mfma_f32_16x16x32_bf16(af1, bw, h1, 0,0,0);
    int col = ct*16 + l15;
    #pragma unroll
    for (int r=0;r<4;r++){
      float v0 = h0[r];
      v0 = v0 / (1.f + __expf(-v0));
      hm[w*32 + q*4 + r][col] = f2bf(v0);
      float v1 = h1[r];
      v1 = v1 / (1.f + __expf(-v1));
      hm[w*32 + 16 + q*4 + r][col] = f2bf(v1);
    }
  }

  // ---- stage 2: msg_hidden = silu(an@mw1a + ah@W_combo + b_combo) -> hm (overwrite) ----
  bf8 ah0[4], ah1[4];
  #pragma unroll
  for (int kt=0;kt<4;kt++){
    ah0[kt] = *(const bf8*)&hm[w*32 + l15][kt*32 + q*8];
    ah1[kt] = *(const bf8*)&hm[w*32 + 16 + l15][kt*32 + q*8];
  }
  #pragma unroll
  for (int ct=0; ct<8; ct++){
    bf8 bw1[4], bwc[4];
    #pragma unroll
    for (int kt=0;kt<4;kt++){
      bw1[kt] = *(const bf8*)(mw1t + (ct*16 + l15)*256 + kt*32 + q*8);
      bwc[kt] = *(const bf8*)(wcombot + (ct*16 + l15)*HD + kt*32 + q*8);
    }
    f32x4 acc0 = {0.f,0.f,0.f,0.f}, acc1 = {0.f,0.f,0.f,0.f};
    #pragma unroll
    for (int kt=0;kt<4;kt++){
      acc0 = __builtin_amdgcn_mfma_f32_16x16x32_bf16(an0[kt], bw1[kt], acc0, 0,0,0);
      acc1 = __builtin_amdgcn_mfma_f32_16x16x32_bf16(an1[kt], bw1[kt], acc1, 0,0,0);
    }
    #pragma unroll
    for (int kt=0;kt<4;kt++){
      acc0 = __builtin_amdgcn_mfma_f32_16x16x32_bf16(ah0[kt], bwc[kt], acc0, 0,0,0);
      acc1 = __builtin_amdgcn_mfma_f32_16x16x32_bf16(ah1[kt], bwc[kt], acc1, 0,0,0);
    }
    float bias = bcombo[ct*16 + l15];
    int col = ct*16 + l15;
    #pragma unroll
    for (int r=0;r<4;r++){
      float v0 = acc0[r] + bias;
      v0 = v0 / (1.f + __expf(-v0));
      hm[w*32 + q*4 + r][col] = f2bf(v0);
      float v1 = acc1[r] + bias;
      v1 = v1 / (1.f + __expf(-v1));
      hm[w*32 + 16 + q*4 + r][col] = f2bf(v1);
    }
  }

  bf8 am0[4], am1[4];
  #pragma unroll
  for (int kt=0;kt<4;kt++){
    am0[kt] = *(const bf8*)&hm[w*32 + l15][kt*32 + q*8];
    am1[kt] = *(const bf8*)&hm[w*32 + 16 + l15][kt*32 + q*8];
  }

  float* msgf_w = (float*)&hm[w*32][0];   // per-wave fp32 arena [16][132]
  int lim0 = E_EDGES - base;      if (lim0 > 16) lim0 = 16;
  int lim1 = E_EDGES - base - 16; if (lim1 > 16) lim1 = 16;
  int c2 = lane*2;
  int cur = -1; float sx = 0.f, sy = 0.f;

  // ---- tile0 msg GEMM -> wave-local segmented reduce ----
  #pragma unroll
  for (int ct=0; ct<8; ct++){
    f32x4 acc = {0.f,0.f,0.f,0.f};
    #pragma unroll
    for (int kt=0;kt<4;kt++){
      bf8 b = *(const bf8*)(mw2t + (ct*16 + l15)*HD + kt*32 + q*8);
      acc = __builtin_amdgcn_mfma_f32_16x16x32_bf16(am0[kt], b, acc, 0,0,0);
    }
    float bias = mb2[ct*16 + l15];
    int col = ct*16 + l15;
    #pragma unroll
    for (int r=0;r<4;r++) msgf_w[(q*4 + r)*132 + col] = acc[r] + bias;
  }
  if (lim0 > 0){
    cur = tgtl[w*32];
    for (int r=0; r<lim0; r++){
      int tg = tgtl[w*32 + r];
      float2 v = *(const float2*)&msgf_w[r*132 + c2];
      if (tg != cur){
        atomicAdd(&agg[(size_t)cur*HD + c2], sx);
        atomicAdd(&agg[(size_t)cur*HD + c2 + 1], sy);
        cur = tg; sx = v.x; sy = v.y;
      } else { sx += v.x; sy += v.y; }
    }
  }

  // ---- tile1 ----
  if (lim1 > 0){
    #pragma unroll
    for (int ct=0; ct<8; ct++){
      f32x4 acc = {0.f,0.f,0.f,0.f};
      #pragma unroll
      for (int kt=0;kt<4;kt++){
        bf8 b = *(const bf8*)(mw2t + (ct*16 + l15)*HD + kt*32 + q*8);
        acc = __builtin_amdgcn_mfma_f32_16x16x32_bf16(am1[kt], b, acc, 0,0,0);
      }
      float bias = mb2[ct*16 + l15];
      int col = ct*16 + l15;
      #pragma unroll
      for (int r=0;r<4;r++) msgf_w[(q*4 + r)*132 + col] = acc[r] + bias;
    }
    for (int r=0; r<lim1; r++){
      int tg = tgtl[w*32 + 16 + r];
      float2 v = *(const float2*)&msgf_w[r*132 + c2];
      if (tg != cur){
        atomicAdd(&agg[(size_t)cur*HD + c2], sx);
        atomicAdd(&agg[(size_t)cur*HD + c2 + 1], sy);
        cur = tg; sx = v.x; sy = v.y;
      } else { sx += v.x; sy += v.y; }
    }
  }
  if (cur >= 0){
    atomicAdd(&agg[(size_t)cur*HD + c2], sx);
    atomicAdd(&agg[(size_t)cur*HD + c2 + 1], sy);
  }
}

// ---------- update MLP (MFMA bf16, wave-local, no barrier), in-place over agg(=d_out) ----------
__global__ void update_mlp2_k(const float* __restrict__ agg, const int* __restrict__ offs,
                              const short* __restrict__ w1t, const float* __restrict__ b1,
                              const short* __restrict__ w2t, const float* __restrict__ b2,
                              float* __restrict__ out)
{
  __shared__ short hid[64][136];
  const int t = threadIdx.x;
  const int wave = t >> 6, lane = t & 63, l15 = lane & 15, q = lane >> 4;
  const int rw = blockIdx.x*64 + wave*16;

  int row = rw + l15;
  float c = (float)(offs[row+1] - offs[row]);
  float rcp = 1.0f / fmaxf(c, 1.0f);
  bf8 a[4];
  const float* ar = agg + (size_t)row*HD;
  #pragma unroll
  for (int kt=0; kt<4; kt++) a[kt] = load_pack8(ar + kt*32 + q*8, rcp);

  #pragma unroll
  for (int ct=0; ct<8; ct++){
    f32x4 acc = {0.f,0.f,0.f,0.f};
    #pragma unroll
    for (int kt=0; kt<4; kt++){
      bf8 b = *(const bf8*)(w1t + (ct*16 + l15)*HD + kt*32 + q*8);
      acc = __builtin_amdgcn_mfma_f32_16x16x32_bf16(a[kt], b, acc, 0, 0, 0);
    }
    float bias = b1[ct*16 + l15];
    #pragma unroll
    for (int r=0;r<4;r++){
      float v = acc[r] + bias;
      v = v / (1.f + __expf(-v));
      hid[wave*16 + q*4 + r][ct*16 + l15] = f2bf(v);
    }
  }
  bf8 a2[4];
  #pragma unroll
  for (int kt=0;kt<4;kt++) a2[kt] = *(const bf8*)&hid[wave*16 + l15][kt*32 + q*8];
  #pragma unroll
  for (int ct=0; ct<8; ct++){
    f32x4 acc = {0.f,0.f,0.f,0.f};
    #pragma unroll
    for (int kt=0;kt<4;kt++){
      bf8 b = *(const bf8*)(w2t + (ct*16 + l15)*HD + kt*32 + q*8);
      acc = __builtin_amdgcn_mfma_f32_16x16x32_bf16(a2[kt], b, acc, 0, 0, 0);
    }
    float bias = b2[ct*16 + l15];
    #pragma unroll
    for (int r=0;r<4;r++)
      out[(size_t)(rw + q*4 + r)*HD + ct*16 + l15] = acc[r] + bias;
  }
}

extern "C" void kernel_launch(void* const* d_in, const int* in_sizes, int n_in,
                              void* d_out, int out_size, void* d_ws, size_t ws_size,
                              hipStream_t stream)
{
  const float* node_features = (const float*)d_in[0];
  const float* node_pos      = (const float*)d_in[1];
  const float* grid_pos      = (const float*)d_in[2];
  const int*   edge_index    = (const int*)d_in[3];
  const float* nm_w1 = (const float*)d_in[4];
  const float* nm_b1 = (const float*)d_in[5];
  const float* nm_w2 = (const float*)d_in[6];
  const float* nm_b2 = (const float*)d_in[7];
  const float* em_w1 = (const float*)d_in[8];
  const float* em_b1 = (const float*)d_in[9];
  const float* em_w2 = (const float*)d_in[10];
  const float* em_b2 = (const float*)d_in[11];
  const float* mm_w1 = (const float*)d_in[12];
  const float* mm_b1 = (const float*)d_in[13];
  const float* mm_w2 = (const float*)d_in[14];
  const float* mm_b2 = (const float*)d_in[15];
  const float* um_w1 = (const float*)d_in[16];
  const float* um_b1 = (const float*)d_in[17];
  const float* um_w2 = (const float*)d_in[18];
  const float* um_b2 = (const float*)d_in[19];
  float* out = (float*)d_out;

  char* ws = (char*)d_ws;
  short* nf     = (short*)ws;                        // 16 MB  bf16 (only first 32768 rows used)
  int*   counts = (int*)  (ws + 16777216ull);        // 128 KB
  int*   offs   = (int*)  (ws + 16908288ull);        // 128 KB + 64
  short* wts    = (short*)(ws + 17039424ull);        // 256 KB bf16 transposed
  short* wcombot= (short*)(ws + 17301568ull);        // 32 KB
  float* bcombo = (float*)(ws + 17334336ull);        // 512 B
  short* ew1x   = (short*)(ws + 17334848ull);        // 8 KB  double-bf16 stage1 B
  int*   srcs_s = (int*)  (ws + 17343040ull);        // 2.4 MB
  int*   tgts_s = (int*)  (ws + 19743040ull);        // 2.4 MB

  short* nmw1t = wts;
  short* nmw2t = wts + 16384;
  short* mmw1t = wts + 49152;   // [n][256]
  short* mmw2t = wts + 81920;
  short* umw1t = wts + 98304;
  short* umw2t = wts + 114688;

  float* agg = out;  // accumulate mean-numerator directly in d_out

  (void)hipMemsetAsync(counts, 0, 131072, stream);
  (void)hipMemsetAsync(out, 0, (size_t)G_GRID*HD*4, stream);

  prep_w_k<<<512, 256, 0, stream>>>(nm_w1, nm_w2, em_w2, mm_w1, mm_w2, um_w1, um_w2, wts);
  prep_combo2_k<<<129, 256, 0, stream>>>(em_w1, em_b1, em_w2, em_b2, mm_w1, mm_b1,
                                         wcombot, bcombo, ew1x);
  // src indices are drawn from [0, G_GRID): only first 32768 nf rows are ever read
  node_mlp_k<<<G_GRID/64, 256, 0, stream>>>(node_features, nmw1t, nm_b1, nmw2t, nm_b2, nf);
  count_k<<<(E_EDGES+255)/256, 256, 0, stream>>>(edge_index, counts);
  scan_k<<<1, 1024, 0, stream>>>(counts, offs);
  scatter_k<<<(E_EDGES+255)/256, 256, 0, stream>>>(edge_index, offs, counts, srcs_s, tgts_s);
  edge_msg6_k<<<(E_EDGES + 127)/128, 256, 0, stream>>>(srcs_s, tgts_s, node_pos, grid_pos,
      ew1x, bcombo, mmw1t, wcombot, mmw2t, mm_b2, nf, agg);
  update_mlp2_k<<<G_GRID/64, 256, 0, stream>>>(agg, offs, umw1t, um_b1, umw2t, um_b2, out);
}

// Round 11
// 528.395 us; speedup vs baseline: 1.0284x; 1.0284x over previous
//
#include <hip/hip_runtime.h>

#define N_NODES 65536
#define G_GRID  32768
#define E_EDGES 600000
#define HD      128

typedef __attribute__((ext_vector_type(8))) short bf8;
typedef __attribute__((ext_vector_type(4))) float f32x4;

__device__ __forceinline__ short f2bf(float f){
  union { float f; unsigned u; } v; v.f = f;
  unsigned r = v.u + 0x7FFFu + ((v.u >> 16) & 1u);
  return (short)(r >> 16);
}
__device__ __forceinline__ float bf2f(short s){
  union { unsigned u; float f; } v; v.u = ((unsigned)(unsigned short)s) << 16; return v.f;
}

__device__ __forceinline__ bf8 load_pack8(const float* p, float scale){
  float4 u0 = *(const float4*)p;
  float4 u1 = *(const float4*)(p + 4);
  bf8 r;
  r[0]=f2bf(u0.x*scale); r[1]=f2bf(u0.y*scale); r[2]=f2bf(u0.z*scale); r[3]=f2bf(u0.w*scale);
  r[4]=f2bf(u1.x*scale); r[5]=f2bf(u1.y*scale); r[6]=f2bf(u1.z*scale); r[7]=f2bf(u1.w*scale);
  return r;
}

// ---------- fused setup: weight transpose + combo fold + edge count ----------
// blocks [0,512): prep_w | [512,640): wcombot k-slices | block 640: bcombo+ew1x | [641,...): count
__global__ void setup_k(const float* __restrict__ nmw1, const float* __restrict__ nmw2,
                        const float* __restrict__ mmw1, const float* __restrict__ mmw2,
                        const float* __restrict__ umw1, const float* __restrict__ umw2,
                        const float* __restrict__ emw1, const float* __restrict__ eb1,
                        const float* __restrict__ emw2, const float* __restrict__ eb2,
                        const float* __restrict__ mb1,
                        const int* __restrict__ eidx,
                        short* __restrict__ wts, short* __restrict__ wcombot,
                        float* __restrict__ bcombo, short* __restrict__ ew1x,
                        int* __restrict__ counts)
{
  const int b = blockIdx.x;
  if (b < 512){
    int i = b*256 + threadIdx.x;  // < 131072
    const float* src; int local; bool k256 = false;
    if      (i < 16384){ src = nmw1; local = i; }
    else if (i < 32768){ src = nmw2; local = i - 16384; }
    else if (i < 49152){ src = emw2; local = i - 32768; }
    else if (i < 81920){ src = mmw1; local = i - 49152; k256 = true; }
    else if (i < 98304){ src = mmw2; local = i - 81920; }
    else if (i < 114688){ src = umw1; local = i - 98304; }
    else               { src = umw2; local = i - 114688; }
    int n, k;
    if (k256){ n = local >> 8; k = local & 255; }
    else     { n = local >> 7; k = local & 127; }
    wts[i] = f2bf(src[k*HD + n]);
  } else if (b < 640){
    __shared__ float part[2][128];
    int k = b - 512;
    int t = threadIdx.x, n = t & 127, half = t >> 7;
    float acc = 0.f;
    const float* er = emw2 + k*HD + half*64;
    #pragma unroll 8
    for (int j=0;j<64;j++) acc += er[j] * mmw1[(HD + half*64 + j)*HD + n];
    part[half][n] = acc;
    __syncthreads();
    if (half == 0) wcombot[n*HD + k] = f2bf(part[0][n] + part[1][n]);
  } else if (b == 640){
    int t = threadIdx.x;
    if (t < 128){
      int n = t;
      float acc = mb1[n];
      for (int j=0;j<HD;j++) acc += eb2[j] * mmw1[(HD + j)*HD + n];
      bcombo[n] = acc;
      short v[32];
      #pragma unroll
      for (int i=0;i<32;i++) v[i] = 0;
      #pragma unroll
      for (int i=0;i<6;i++){
        float wv = emw1[i*HD + n];
        short wh = f2bf(wv);
        short wl = f2bf(wv - bf2f(wh));
        v[i] = wh; v[6+i] = wh; v[12+i] = wl;
      }
      float bv = eb1[n];
      short bh = f2bf(bv);
      v[18] = bh; v[19] = f2bf(bv - bf2f(bh));
      #pragma unroll
      for (int i=0;i<32;i++) ew1x[n*32 + i] = v[i];
    }
  } else {
    int e = (b - 641)*256 + threadIdx.x;
    if (e < E_EDGES) atomicAdd(&counts[eidx[E_EDGES + e]], 1);
  }
}

// ---------- node MLP (MFMA, wave-local hid slab -> no barrier) ----------
__global__ void node_mlp_k(const float* __restrict__ X,
                           const short* __restrict__ w1t, const float* __restrict__ b1,
                           const short* __restrict__ w2t, const float* __restrict__ b2,
                           short* __restrict__ nf)
{
  __shared__ short hid[64][136];
  const int t = threadIdx.x;
  const int wave = t >> 6, lane = t & 63, l15 = lane & 15, q = lane >> 4;
  const int rw = blockIdx.x*64 + wave*16;

  bf8 a[4];
  const float* xr = X + (size_t)(rw + l15)*HD;
  #pragma unroll
  for (int kt=0; kt<4; kt++) a[kt] = load_pack8(xr + kt*32 + q*8, 1.0f);

  #pragma unroll
  for (int ct=0; ct<8; ct++){
    f32x4 acc = {0.f,0.f,0.f,0.f};
    #pragma unroll
    for (int kt=0; kt<4; kt++){
      bf8 b = *(const bf8*)(w1t + (ct*16 + l15)*HD + kt*32 + q*8);
      acc = __builtin_amdgcn_mfma_f32_16x16x32_bf16(a[kt], b, acc, 0, 0, 0);
    }
    float bias = b1[ct*16 + l15];
    #pragma unroll
    for (int r=0;r<4;r++){
      float v = acc[r] + bias;
      v = v / (1.f + __expf(-v));
      hid[wave*16 + q*4 + r][ct*16 + l15] = f2bf(v);
    }
  }
  bf8 a2[4];
  #pragma unroll
  for (int kt=0;kt<4;kt++) a2[kt] = *(const bf8*)&hid[wave*16 + l15][kt*32 + q*8];
  #pragma unroll
  for (int ct=0; ct<8; ct++){
    f32x4 acc = {0.f,0.f,0.f,0.f};
    #pragma unroll
    for (int kt=0;kt<4;kt++){
      bf8 b = *(const bf8*)(w2t + (ct*16 + l15)*HD + kt*32 + q*8);
      acc = __builtin_amdgcn_mfma_f32_16x16x32_bf16(a2[kt], b, acc, 0, 0, 0);
    }
    float bias = b2[ct*16 + l15];
    #pragma unroll
    for (int r=0;r<4;r++)
      nf[(size_t)(rw + q*4 + r)*HD + ct*16 + l15] = f2bf(acc[r] + bias);
  }
}

// ---------- CSR build ----------
__global__ void scan_k(const int* __restrict__ counts, int* __restrict__ offs){
  __shared__ int part[1024];
  const int t = threadIdx.x;
  const int base = t*32;
  int loc[32];
  int s = 0;
  #pragma unroll
  for (int i=0;i<32;i++){ loc[i] = s; s += counts[base+i]; }
  part[t] = s;
  __syncthreads();
  for (int off=1; off<1024; off<<=1){
    int v = (t>=off) ? part[t-off] : 0;
    __syncthreads();
    part[t] += v;
    __syncthreads();
  }
  int pre = (t==0) ? 0 : part[t-1];
  #pragma unroll
  for (int i=0;i<32;i++) offs[base+i] = pre + loc[i];
  if (t==1023) offs[G_GRID] = pre + s;
}

// consumes counts; also packs pos6[slot] = {npos[s], gpos[g]} so the edge kernel
// reads positions with 2 coalesced 16B loads instead of 12 scattered dwords.
__global__ void scatter_k(const int* __restrict__ eidx, const int* __restrict__ offs,
                          int* __restrict__ counts,
                          int* __restrict__ srcs_s, int* __restrict__ tgts_s,
                          const float* __restrict__ npos, const float* __restrict__ gpos,
                          float* __restrict__ pos6){
  int e = blockIdx.x*256 + threadIdx.x;
  if (e < E_EDGES){
    int s = eidx[e];
    int g = eidx[E_EDGES + e];
    int slot = offs[g] + atomicSub(&counts[g], 1) - 1;
    srcs_s[slot] = s;
    tgts_s[slot] = g;
    float* pd = pos6 + (size_t)slot*8;
    pd[0]=npos[s*3+0]; pd[1]=npos[s*3+1]; pd[2]=npos[s*3+2];
    pd[3]=gpos[g*3+0]; pd[4]=gpos[g*3+1]; pd[5]=gpos[g*3+2];
    pd[6]=0.f; pd[7]=0.f;
  }
}

// A-frag builder for double-bf16 stage1: A=[ph0..5|pl0..5 slices per quad|1,1 pad]
__device__ __forceinline__ bf8 build_af(const float p[6], int q){
  short ph[6], pl[6];
  #pragma unroll
  for (int i=0;i<6;i++){
    ph[i] = f2bf(p[i]);
    pl[i] = f2bf(p[i] - bf2f(ph[i]));
  }
  bf8 af = {0,0,0,0,0,0,0,0};
  if (q == 0){
    af[0]=ph[0]; af[1]=ph[1]; af[2]=ph[2]; af[3]=ph[3];
    af[4]=ph[4]; af[5]=ph[5]; af[6]=pl[0]; af[7]=pl[1];
  } else if (q == 1){
    af[0]=pl[2]; af[1]=pl[3]; af[2]=pl[4]; af[3]=pl[5];
    af[4]=ph[0]; af[5]=ph[1]; af[6]=ph[2]; af[7]=ph[3];
  } else if (q == 2){
    af[0]=ph[4]; af[1]=ph[5]; af[2]=(short)0x3F80; af[3]=(short)0x3F80;
  }
  return af;
}

// ---------- fused edge+message: ZERO barriers, stage1 via MFMA, packed pos loads ----------
__global__ void __launch_bounds__(256, 3)
edge_msg7_k(const int* __restrict__ srcs_s, const int* __restrict__ tgts_s,
            const float* __restrict__ pos6,
            const short* __restrict__ ew1x, const float* __restrict__ bcombo,
            const short* __restrict__ mw1t, const short* __restrict__ wcombot,
            const short* __restrict__ mw2t, const float* __restrict__ mb2,
            const short* __restrict__ nf, float* __restrict__ agg)
{
  __shared__ int tgtl[128];         // per-wave staged (lanes<32), no barrier
  __shared__ short hm[128][136];    // 34816 B -> total 35328 B

  const int t = threadIdx.x;
  const int e0 = blockIdx.x*128;
  const int w = t >> 6, lane = t & 63, l15 = lane & 15, q = lane >> 4;
  const int base = e0 + w*32;

  // ---- early gathers ----
  int i0 = base + l15;      if (i0 >= E_EDGES) i0 = E_EDGES - 1;
  int i1 = base + 16 + l15; if (i1 >= E_EDGES) i1 = E_EDGES - 1;
  int s0 = srcs_s[i0], s1 = srcs_s[i1];

  bf8 an0[4], an1[4];
  {
    const short* n0p = nf + (size_t)s0*HD + q*8;
    const short* n1p = nf + (size_t)s1*HD + q*8;
    #pragma unroll
    for (int kt=0;kt<4;kt++){ an0[kt] = *(const bf8*)(n0p + kt*32); an1[kt] = *(const bf8*)(n1p + kt*32); }
  }
  // packed pos: 2x16B coalesced loads per tile
  float pA[6], pB[6];
  {
    const float* pp = pos6 + (size_t)i0*8;
    f32x4 u0 = *(const f32x4*)pp;
    f32x4 u1 = *(const f32x4*)(pp + 4);
    pA[0]=u0[0]; pA[1]=u0[1]; pA[2]=u0[2]; pA[3]=u0[3]; pA[4]=u1[0]; pA[5]=u1[1];
    const float* pq = pos6 + (size_t)i1*8;
    f32x4 v0 = *(const f32x4*)pq;
    f32x4 v1 = *(const f32x4*)(pq + 4);
    pB[0]=v0[0]; pB[1]=v0[1]; pB[2]=v0[2]; pB[3]=v0[3]; pB[4]=v1[0]; pB[5]=v1[1];
  }

  // per-wave tgt staging (wave-local write+read -> no __syncthreads)
  if (lane < 32){
    int idx = base + lane; if (idx >= E_EDGES) idx = E_EDGES - 1;
    tgtl[w*32 + lane] = tgts_s[idx];
  }

  // ---- stage 1: h = silu(pos6@ew1+eb1) via ONE MFMA per ct per tile (double-bf16, exact) ----
  bf8 af0 = build_af(pA, q);
  bf8 af1 = build_af(pB, q);
  #pragma unroll
  for (int ct=0; ct<8; ct++){
    bf8 bw = *(const bf8*)(ew1x + (ct*16 + l15)*32 + q*8);
    f32x4 h0 = {0.f,0.f,0.f,0.f}, h1 = {0.f,0.f,0.f,0.f};
    h0 = __builtin_amdgcn_mfma_f32_16x16x32_bf16(af0, bw, h0, 0,0,0);
    h1 = __builtin_amdgcn_mfma_f32_16x16x32_bf16(af1, bw, h1, 0,0,0);
    int col = ct*16 + l15;
    #pragma unroll
    for (int r=0;r<4;r++){
      float v0 = h0[r];
      v0 = v0 / (1.f + __expf(-v0));
      hm[w*32 + q*4 + r][col] = f2bf(v0);
      float v1 = h1[r];
      v1 = v1 / (1.f + __expf(-v1));
      hm[w*32 + 16 + q*4 + r][col] = f2bf(v1);
    }
  }

  // ---- stage 2: msg_hidden = silu(an@mw1a + ah@W_combo + b_combo) -> hm (overwrite) ----
  bf8 ah0[4], ah1[4];
  #pragma unroll
  for (int kt=0;kt<4;kt++){
    ah0[kt] = *(const bf8*)&hm[w*32 + l15][kt*32 + q*8];
    ah1[kt] = *(const bf8*)&hm[w*32 + 16 + l15][kt*32 + q*8];
  }
  #pragma unroll
  for (int ct=0; ct<8; ct++){
    bf8 bw1[4], bwc[4];
    #pragma unroll
    for (int kt=0;kt<4;kt++){
      bw1[kt] = *(const bf8*)(mw1t + (ct*16 + l15)*256 + kt*32 + q*8);
      bwc[kt] = *(const bf8*)(wcombot + (ct*16 + l15)*HD + kt*32 + q*8);
    }
    f32x4 acc0 = {0.f,0.f,0.f,0.f}, acc1 = {0.f,0.f,0.f,0.f};
    #pragma unroll
    for (int kt=0;kt<4;kt++){
      acc0 = __builtin_amdgcn_mfma_f32_16x16x32_bf16(an0[kt], bw1[kt], acc0, 0,0,0);
      acc1 = __builtin_amdgcn_mfma_f32_16x16x32_bf16(an1[kt], bw1[kt], acc1, 0,0,0);
    }
    #pragma unroll
    for (int kt=0;kt<4;kt++){
      acc0 = __builtin_amdgcn_mfma_f32_16x16x32_bf16(ah0[kt], bwc[kt], acc0, 0,0,0);
      acc1 = __builtin_amdgcn_mfma_f32_16x16x32_bf16(ah1[kt], bwc[kt], acc1, 0,0,0);
    }
    float bias = bcombo[ct*16 + l15];
    int col = ct*16 + l15;
    #pragma unroll
    for (int r=0;r<4;r++){
      float v0 = acc0[r] + bias;
      v0 = v0 / (1.f + __expf(-v0));
      hm[w*32 + q*4 + r][col] = f2bf(v0);
      float v1 = acc1[r] + bias;
      v1 = v1 / (1.f + __expf(-v1));
      hm[w*32 + 16 + q*4 + r][col] = f2bf(v1);
    }
  }

  bf8 am0[4], am1[4];
  #pragma unroll
  for (int kt=0;kt<4;kt++){
    am0[kt] = *(const bf8*)&hm[w*32 + l15][kt*32 + q*8];
    am1[kt] = *(const bf8*)&hm[w*32 + 16 + l15][kt*32 + q*8];
  }

  float* msgf_w = (float*)&hm[w*32][0];   // per-wave fp32 arena [16][132]
  int lim0 = E_EDGES - base;      if (lim0 > 16) lim0 = 16;
  int lim1 = E_EDGES - base - 16; if (lim1 > 16) lim1 = 16;
  int c2 = lane*2;
  int cur = -1; float sx = 0.f, sy = 0.f;

  // ---- tile0 msg GEMM -> wave-local segmented reduce ----
  #pragma unroll
  for (int ct=0; ct<8; ct++){
    f32x4 acc = {0.f,0.f,0.f,0.f};
    #pragma unroll
    for (int kt=0;kt<4;kt++){
      bf8 b = *(const bf8*)(mw2t + (ct*16 + l15)*HD + kt*32 + q*8);
      acc = __builtin_amdgcn_mfma_f32_16x16x32_bf16(am0[kt], b, acc, 0,0,0);
    }
    float bias = mb2[ct*16 + l15];
    int col = ct*16 + l15;
    #pragma unroll
    for (int r=0;r<4;r++) msgf_w[(q*4 + r)*132 + col] = acc[r] + bias;
  }
  if (lim0 > 0){
    cur = tgtl[w*32];
    for (int r=0; r<lim0; r++){
      int tg = tgtl[w*32 + r];
      float2 v = *(const float2*)&msgf_w[r*132 + c2];
      if (tg != cur){
        atomicAdd(&agg[(size_t)cur*HD + c2], sx);
        atomicAdd(&agg[(size_t)cur*HD + c2 + 1], sy);
        cur = tg; sx = v.x; sy = v.y;
      } else { sx += v.x; sy += v.y; }
    }
  }

  // ---- tile1 ----
  if (lim1 > 0){
    #pragma unroll
    for (int ct=0; ct<8; ct++){
      f32x4 acc = {0.f,0.f,0.f,0.f};
      #pragma unroll
      for (int kt=0;kt<4;kt++){
        bf8 b = *(const bf8*)(mw2t + (ct*16 + l15)*HD + kt*32 + q*8);
        acc = __builtin_amdgcn_mfma_f32_16x16x32_bf16(am1[kt], b, acc, 0,0,0);
      }
      float bias = mb2[ct*16 + l15];
      int col = ct*16 + l15;
      #pragma unroll
      for (int r=0;r<4;r++) msgf_w[(q*4 + r)*132 + col] = acc[r] + bias;
    }
    for (int r=0; r<lim1; r++){
      int tg = tgtl[w*32 + 16 + r];
      float2 v = *(const float2*)&msgf_w[r*132 + c2];
      if (tg != cur){
        atomicAdd(&agg[(size_t)cur*HD + c2], sx);
        atomicAdd(&agg[(size_t)cur*HD + c2 + 1], sy);
        cur = tg; sx = v.x; sy = v.y;
      } else { sx += v.x; sy += v.y; }
    }
  }
  if (cur >= 0){
    atomicAdd(&agg[(size_t)cur*HD + c2], sx);
    atomicAdd(&agg[(size_t)cur*HD + c2 + 1], sy);
  }
}

// ---------- update MLP (MFMA bf16, wave-local, no barrier), in-place over agg(=d_out) ----------
__global__ void update_mlp2_k(const float* __restrict__ agg, const int* __restrict__ offs,
                              const short* __restrict__ w1t, const float* __restrict__ b1,
                              const short* __restrict__ w2t, const float* __restrict__ b2,
                              float* __restrict__ out)
{
  __shared__ short hid[64][136];
  const int t = threadIdx.x;
  const int wave = t >> 6, lane = t & 63, l15 = lane & 15, q = lane >> 4;
  const int rw = blockIdx.x*64 + wave*16;

  int row = rw + l15;
  float c = (float)(offs[row+1] - offs[row]);
  float rcp = 1.0f / fmaxf(c, 1.0f);
  bf8 a[4];
  const float* ar = agg + (size_t)row*HD;
  #pragma unroll
  for (int kt=0; kt<4; kt++) a[kt] = load_pack8(ar + kt*32 + q*8, rcp);

  #pragma unroll
  for (int ct=0; ct<8; ct++){
    f32x4 acc = {0.f,0.f,0.f,0.f};
    #pragma unroll
    for (int kt=0; kt<4; kt++){
      bf8 b = *(const bf8*)(w1t + (ct*16 + l15)*HD + kt*32 + q*8);
      acc = __builtin_amdgcn_mfma_f32_16x16x32_bf16(a[kt], b, acc, 0, 0, 0);
    }
    float bias = b1[ct*16 + l15];
    #pragma unroll
    for (int r=0;r<4;r++){
      float v = acc[r] + bias;
      v = v / (1.f + __expf(-v));
      hid[wave*16 + q*4 + r][ct*16 + l15] = f2bf(v);
    }
  }
  bf8 a2[4];
  #pragma unroll
  for (int kt=0;kt<4;kt++) a2[kt] = *(const bf8*)&hid[wave*16 + l15][kt*32 + q*8];
  #pragma unroll
  for (int ct=0; ct<8; ct++){
    f32x4 acc = {0.f,0.f,0.f,0.f};
    #pragma unroll
    for (int kt=0;kt<4;kt++){
      bf8 b = *(const bf8*)(w2t + (ct*16 + l15)*HD + kt*32 + q*8);
      acc = __builtin_amdgcn_mfma_f32_16x16x32_bf16(a2[kt], b, acc, 0, 0, 0);
    }
    float bias = b2[ct*16 + l15];
    #pragma unroll
    for (int r=0;r<4;r++)
      out[(size_t)(rw + q*4 + r)*HD + ct*16 + l15] = acc[r] + bias;
  }
}

extern "C" void kernel_launch(void* const* d_in, const int* in_sizes, int n_in,
                              void* d_out, int out_size, void* d_ws, size_t ws_size,
                              hipStream_t stream)
{
  const float* node_features = (const float*)d_in[0];
  const float* node_pos      = (const float*)d_in[1];
  const float* grid_pos      = (const float*)d_in[2];
  const int*   edge_index    = (const int*)d_in[3];
  const float* nm_w1 = (const float*)d_in[4];
  const float* nm_b1 = (const float*)d_in[5];
  const float* nm_w2 = (const float*)d_in[6];
  const float* nm_b2 = (const float*)d_in[7];
  const float* em_w1 = (const float*)d_in[8];
  const float* em_b1 = (const float*)d_in[9];
  const float* em_w2 = (const float*)d_in[10];
  const float* em_b2 = (const float*)d_in[11];
  const float* mm_w1 = (const float*)d_in[12];
  const float* mm_b1 = (const float*)d_in[13];
  const float* mm_w2 = (const float*)d_in[14];
  const float* mm_b2 = (const float*)d_in[15];
  const float* um_w1 = (const float*)d_in[16];
  const float* um_b1 = (const float*)d_in[17];
  const float* um_w2 = (const float*)d_in[18];
  const float* um_b2 = (const float*)d_in[19];
  float* out = (float*)d_out;

  char* ws = (char*)d_ws;
  short* nf     = (short*)ws;                        // 16 MB  bf16 (only first 32768 rows used)
  int*   counts = (int*)  (ws + 16777216ull);        // 128 KB
  int*   offs   = (int*)  (ws + 16908288ull);        // 128 KB + 64
  short* wts    = (short*)(ws + 17039424ull);        // 256 KB bf16 transposed
  short* wcombot= (short*)(ws + 17301568ull);        // 32 KB
  float* bcombo = (float*)(ws + 17334336ull);        // 512 B
  short* ew1x   = (short*)(ws + 17334848ull);        // 8 KB  double-bf16 stage1 B
  int*   srcs_s = (int*)  (ws + 17343040ull);        // 2.4 MB
  int*   tgts_s = (int*)  (ws + 19743040ull);        // 2.4 MB
  float* pos6   = (float*)(ws + 22143040ull);        // 19.2 MB packed pos per sorted edge

  short* nmw1t = wts;
  short* nmw2t = wts + 16384;
  short* mmw1t = wts + 49152;   // [n][256]
  short* mmw2t = wts + 81920;
  short* umw1t = wts + 98304;
  short* umw2t = wts + 114688;

  float* agg = out;  // accumulate mean-numerator directly in d_out

  (void)hipMemsetAsync(counts, 0, 131072, stream);
  (void)hipMemsetAsync(out, 0, (size_t)G_GRID*HD*4, stream);

  const int count_blocks = (E_EDGES + 255)/256;  // 2344
  setup_k<<<641 + count_blocks, 256, 0, stream>>>(nm_w1, nm_w2, mm_w1, mm_w2, um_w1, um_w2,
      em_w1, em_b1, em_w2, em_b2, mm_b1, edge_index, wts, wcombot, bcombo, ew1x, counts);
  // src indices are drawn from [0, G_GRID): only first 32768 nf rows are ever read
  node_mlp_k<<<G_GRID/64, 256, 0, stream>>>(node_features, nmw1t, nm_b1, nmw2t, nm_b2, nf);
  scan_k<<<1, 1024, 0, stream>>>(counts, offs);
  scatter_k<<<count_blocks, 256, 0, stream>>>(edge_index, offs, counts, srcs_s, tgts_s,
      node_pos, grid_pos, pos6);
  edge_msg7_k<<<(E_EDGES + 127)/128, 256, 0, stream>>>(srcs_s, tgts_s, pos6,
      ew1x, bcombo, mmw1t, wcombot, mmw2t, mm_b2, nf, agg);
  update_mlp2_k<<<G_GRID/64, 256, 0, stream>>>(agg, offs, umw1t, um_b1, umw2t, um_b2, out);
}